// Round 3
// baseline (260.755 us; speedup 1.0000x reference)
//
#include <hip/hip_runtime.h>

typedef unsigned long long u64;
typedef unsigned u32;

#define B_ROWS  262144
#define N_NEG   1310720
#define NB      4096          // buckets = key >> 20
#define CAP     512           // max bucket size (E=320, 10.7 sigma headroom)
#define NCHUNK  128
#define EPT     40            // N_NEG / (NCHUNK*256)

// ---------------- ws layout (bytes) ----------------
#define OFF_PAIRS1  0u          // N_NEG*8
#define OFF_PAIRS2  10485760u   // N_NEG*8
#define OFF_STATT   20971520u   // B*8
#define OFF_STATF   23068672u   // B*8
#define OFF_POSD    25165824u   // B*4
#define OFF_HIST1   26214400u   // 4096*4
#define OFF_HIST2   26230784u   // 4096*4
#define OFF_SLOTS   26247168u   // 6*256*8
#define OFF_TOTX1   26259456u   // 4097*4 (+pad)
#define OFF_TOTX2   26275848u
#define OFF_CUR1    26292240u   // 4096*4
#define OFF_CUR2    26308624u
#define WS_NEEDED   26325008u
#define MEMSET_OFF  OFF_HIST1
#define MEMSET_SZ   45056u      // hist1+hist2+slots contiguous

struct U2 { unsigned a, b; };

// Threefry-2x32, 20 rounds — matches jax/_src/prng.py threefry2x32.
__host__ __device__ inline U2 tf2x32(unsigned k0, unsigned k1, unsigned c0, unsigned c1) {
  unsigned ks2 = k0 ^ k1 ^ 0x1BD11BDAu;
  unsigned x0 = c0 + k0, x1 = c1 + k1;
#define ROTL(x,d) (((x) << (d)) | ((x) >> (32 - (d))))
#define R4(r0,r1,r2,r3) \
  x0 += x1; x1 = ROTL(x1, r0); x1 ^= x0; \
  x0 += x1; x1 = ROTL(x1, r1); x1 ^= x0; \
  x0 += x1; x1 = ROTL(x1, r2); x1 ^= x0; \
  x0 += x1; x1 = ROTL(x1, r3); x1 ^= x0;
  R4(13,15,26,6)   x0 += k1;  x1 += ks2 + 1u;
  R4(17,29,16,24)  x0 += ks2; x1 += k0  + 2u;
  R4(13,15,26,6)   x0 += k0;  x1 += k1  + 3u;
  R4(17,29,16,24)  x0 += k1;  x1 += ks2 + 4u;
  R4(13,15,26,6)   x0 += ks2; x1 += k0  + 5u;
#undef R4
#undef ROTL
  return U2{x0, x1};
}

__device__ inline u32 keyfn(unsigned k0, unsigned k1, u32 i) {
  U2 c = tf2x32(k0, k1, 0u, i);
  return c.a ^ c.b;
}

// ---------- block reduce: thread 0 ends with totals in v[] ----------
template <int N>
__device__ inline void block_sum(double* v) {
  __shared__ double sh[N][4];
  int lane = threadIdx.x & 63, w = threadIdx.x >> 6;
#pragma unroll
  for (int j = 0; j < N; ++j) {
    double x = v[j];
    for (int o = 32; o > 0; o >>= 1) x += __shfl_down(x, o);
    if (lane == 0) sh[j][w] = x;
  }
  __syncthreads();
  if (threadIdx.x == 0)
#pragma unroll
    for (int j = 0; j < N; ++j) v[j] = sh[j][0] + sh[j][1] + sh[j][2] + sh[j][3];
  __syncthreads();
}

// ---------------- pipeline kernels ----------------

// global bucket histograms for both rounds (keys computed on the fly)
__global__ __launch_bounds__(256)
void k_count(u32* __restrict__ hist1, u32* __restrict__ hist2,
             u32 k10, u32 k11, u32 k20, u32 k21) {
  __shared__ u32 h[2 * NB];
  int t = threadIdx.x;
  for (int b = t; b < 2 * NB; b += 256) h[b] = 0;
  __syncthreads();
  u32 base = blockIdx.x * (EPT * 256);
  for (int e = 0; e < EPT; ++e) {
    u32 i = base + e * 256 + t;
    atomicAdd(&h[keyfn(k10, k11, i) >> 20], 1u);
    atomicAdd(&h[NB + (keyfn(k20, k21, i) >> 20)], 1u);
  }
  __syncthreads();
  for (int b = t; b < NB; b += 256) {
    u32 a = h[b], c = h[NB + b];
    if (a) atomicAdd(&hist1[b], a);
    if (c) atomicAdd(&hist2[b], c);
  }
}

// exclusive scan of both 4096-bucket histograms; init atomic cursors
__global__ void k_scan(const u32* __restrict__ hist1, const u32* __restrict__ hist2,
                       u32* __restrict__ totx1, u32* __restrict__ totx2,
                       u32* __restrict__ cur1, u32* __restrict__ cur2) {
  const u32* src = blockIdx.x ? hist2 : hist1;
  u32* totx = blockIdx.x ? totx2 : totx1;
  u32* cur  = blockIdx.x ? cur2 : cur1;
  int t = threadIdx.x;
  u32 loc[16]; u32 s = 0;
#pragma unroll
  for (int q = 0; q < 16; ++q) { loc[q] = src[t * 16 + q]; s += loc[q]; }
  __shared__ u32 sh[256];
  sh[t] = s; __syncthreads();
  for (int o = 1; o < 256; o <<= 1) {
    u32 x = (t >= o) ? sh[t - o] : 0u; __syncthreads();
    sh[t] += x; __syncthreads();
  }
  u32 run = sh[t] - s;
#pragma unroll
  for (int q = 0; q < 16; ++q) { totx[t * 16 + q] = run; cur[t * 16 + q] = run; run += loc[q]; }
  if (t == 255) totx[NB] = run;
}

// round-1 scatter: pairs1[slot] = (key1<<32)|i  via global atomic cursors
__global__ __launch_bounds__(256)
void k_scatter1(u64* __restrict__ pairs1, u32* __restrict__ cur1, u32 k0, u32 k1) {
  int t = threadIdx.x;
  u32 base = blockIdx.x * (EPT * 256);
  for (int e = 0; e < EPT; ++e) {
    u32 i = base + e * 256 + t;
    u32 key = keyfn(k0, k1, i);
    u32 slot = atomicAdd(&cur1[key >> 20], 1u);
    pairs1[slot] = ((u64)key << 32) | i;
  }
}

// counting-sort ranking within a bucket (keys in skey[0..c), binx[257] bins)
// digit = bits [SH+7 : SH] of the u64 key
#define RANK_PROLOG(PAIRS, TOTX, SH)                                          \
  __shared__ u64 karr[CAP];                                                   \
  __shared__ u64 skey[CAP];                                                   \
  __shared__ u32 binx[257];                                                   \
  __shared__ u32 bcur[256];                                                   \
  __shared__ u32 tmp[256];                                                    \
  int t = threadIdx.x, b = blockIdx.x;                                        \
  u32 base = TOTX[b];                                                         \
  u32 c = TOTX[b + 1] - base; if (c > CAP) c = CAP;                           \
  binx[t] = 0;                                                                \
  for (int q = 0; q < 2; ++q) {                                               \
    int ii = t + q * 256;                                                     \
    if (ii < (int)c) karr[ii] = PAIRS[base + ii];                             \
  }                                                                           \
  __syncthreads();                                                            \
  for (int q = 0; q < 2; ++q) {                                               \
    int ii = t + q * 256;                                                     \
    if (ii < (int)c) atomicAdd(&binx[(u32)(karr[ii] >> (SH)) & 255u], 1u);    \
  }                                                                           \
  __syncthreads();                                                            \
  u32 v = binx[t]; tmp[t] = v; __syncthreads();                               \
  for (int o = 1; o < 256; o <<= 1) {                                         \
    u32 x = (t >= o) ? tmp[t - o] : 0u; __syncthreads();                      \
    tmp[t] += x; __syncthreads();                                             \
  }                                                                           \
  u32 incl = tmp[t];                                                          \
  binx[t] = incl - v; bcur[t] = incl - v;                                     \
  if (t == 255) binx[256] = incl;                                             \
  __syncthreads();                                                            \
  for (int q = 0; q < 2; ++q) {                                               \
    int ii = t + q * 256;                                                     \
    if (ii < (int)c) {                                                        \
      u64 k = karr[ii];                                                       \
      u32 d = (u32)(k >> (SH)) & 255u;                                        \
      skey[atomicAdd(&bcur[d], 1u)] = k;                                      \
    }                                                                         \
  }                                                                           \
  __syncthreads();

// round-1 rank + round-2 scatter (no interm array, no gathers)
__global__ __launch_bounds__(256)
void k_rank1_scatter2(const u64* __restrict__ pairs1, const u32* __restrict__ totx1,
                      u64* __restrict__ pairs2, u32* __restrict__ cur2,
                      u32 k20, u32 k21) {
  RANK_PROLOG(pairs1, totx1, 44)   // key1 bits [19:12] live at packed bits [51:44]
  for (int q = 0; q < 2; ++q) {
    int s = t + q * 256;
    if (s < (int)c) {
      u64 k = skey[s];
      u32 d = (u32)(k >> 44) & 255u;
      u32 lo = binx[d], hi = binx[d + 1];
      u32 r = lo;
      for (u32 e = lo; e < hi; ++e) r += (skey[e] < k) ? 1u : 0u;
      u32 j = base + r;                      // final round-1 position
      u32 iorig = (u32)k & 0x1FFFFFu;        // original index (< 2^21)
      u32 key2 = keyfn(k20, k21, j);
      u64 packed = ((u64)(key2 & 0xFFFFFu) << 42) | ((u64)j << 21) | (u64)iorig;
      u32 slot = atomicAdd(&cur2[key2 >> 20], 1u);
      pairs2[slot] = packed;
    }
  }
}

// round-2 rank fused with negative-pair loss (no sorted output needed)
__global__ __launch_bounds__(256)
void k_rank2_loss(const u64* __restrict__ pairs2, const u32* __restrict__ totx2,
                  const float* __restrict__ et, const float* __restrict__ ef,
                  const u64* __restrict__ statT, const u64* __restrict__ statF,
                  double* __restrict__ slots) {
  RANK_PROLOG(pairs2, totx2, 54)   // key2 bits [19:12] live at packed bits [61:54]
  double sd = 0.0, sce = 0.0, sn = 0.0;
  for (int q = 0; q < 2; ++q) {
    int s = t + q * 256;
    if (s < (int)c) {
      u64 k = skey[s];
      u32 d = (u32)(k >> 54) & 255u;
      u32 lo = binx[d], hi = binx[d + 1];
      u32 r = lo;
      for (u32 e = lo; e < hi; ++e) r += (skey[e] < k) ? 1u : 0u;
      u32 p = base + r;                      // final permuted position
      u32 i = (u32)k & 0x1FFFFFu;            // original repeat index
      u32 a = p / 5u;
      u32 bb = i / 5u;
      float2 ta = ((const float2*)et)[a];
      float2 fb = ((const float2*)ef)[bb];
      float dx = ta.x - fb.x, dy = ta.y - fb.y;
      float dd = sqrtf(dx * dx + dy * dy);
      u64 st = statT[a], sf = statF[bb];
      int at = (int)(st >> 32), af = (int)(sf >> 32);
      float ct = __uint_as_float((u32)st), cf = __uint_as_float((u32)sf);
      bool keep = !((af == at) && (cf == ct));
      float pp = 1.0f / (1.0f + dd * dd);
      float qc = fminf(fmaxf(1.0f - pp, 1e-4f), 1.0f);
      float ce = -logf(qc);
      if (keep) { sd += (double)dd; sce += (double)ce; sn += 1.0; }
    }
  }
  double vv[3] = {sd, sce, sn};
  block_sum<3>(vv);
  if (t == 0) {
    int slot = b & 255;
    atomicAdd(&slots[2 * 256 + slot], vv[0]);
    atomicAdd(&slots[3 * 256 + slot], vv[1]);
    atomicAdd(&slots[4 * 256 + slot], vv[2]);
  }
}

// ---------------- loss kernels ----------------
__device__ inline void rowstat(const float* __restrict__ row, int& am, float& conf) {
  float v[10];
  const float2* r2 = (const float2*)row;
#pragma unroll
  for (int j = 0; j < 5; ++j) { float2 x = r2[j]; v[2 * j] = x.x; v[2 * j + 1] = x.y; }
  float m = v[0]; int a = 0;
#pragma unroll
  for (int j = 1; j < 10; ++j) if (v[j] > m) { m = v[j]; a = j; }   // first max, like jnp.argmax
  float s = 0.f;
#pragma unroll
  for (int j = 0; j < 10; ++j) s += expf(v[j] - m);
  am = a;
  conf = 1.0f / s;
}

__global__ __launch_bounds__(256)
void k_pos(const float* __restrict__ et, const float* __restrict__ ef,
           const float* __restrict__ probs,
           const float* __restrict__ pto, const float* __restrict__ pfr,
           u64* __restrict__ statT, u64* __restrict__ statF,
           float* __restrict__ posd, double* __restrict__ slots) {
  int i = blockIdx.x * 256 + threadIdx.x;
  int at, af; float ct, cf;
  rowstat(pto + (size_t)i * 10, at, ct);
  rowstat(pfr + (size_t)i * 10, af, cf);
  statT[i] = ((u64)(u32)at << 32) | (u64)__float_as_uint(ct);
  statF[i] = ((u64)(u32)af << 32) | (u64)__float_as_uint(cf);
  float2 a = ((const float2*)et)[i];
  float2 b = ((const float2*)ef)[i];
  float dx = a.x - b.x, dy = a.y - b.y;
  float d = sqrtf(dx * dx + dy * dy);
  posd[i] = (at == af) ? -d : d;          // sign bit encodes is_pred_same
  float pr = probs[i];
  float p  = 1.0f / (1.0f + d * d);
  float pc = fminf(fmaxf(p, 1e-4f), 1.0f);
  float qc = fminf(fmaxf(1.0f - p, 1e-4f), 1.0f);
  float ce = -pr * logf(pc) - (1.0f - pr) * logf(qc);
  double v[2] = {(double)d, (double)ce};
  block_sum<2>(v);
  if (threadIdx.x == 0) {
    int slot = blockIdx.x & 255;
    atomicAdd(&slots[0 * 256 + slot], v[0]);
    atomicAdd(&slots[1 * 256 + slot], v[1]);
  }
}

__global__ __launch_bounds__(256)
void k_margin(const float* __restrict__ posd, double* __restrict__ slots) {
  int t = threadIdx.x;
  double v[3] = { slots[0 * 256 + t], slots[2 * 256 + t], slots[4 * 256 + t] };
  block_sum<3>(v);
  __shared__ float sbm;
  if (t == 0) {
    float pm = (float)(v[0] / (double)B_ROWS);
    float nm = (float)(v[1] / v[2]);
    sbm = (pm + nm) * 0.5f;
  }
  __syncthreads();
  float bm = sbm;
  int i = blockIdx.x * 256 + t;
  float pd = posd[i];
  float cc = 0.f;
  if (!(__float_as_uint(pd) >> 31)) cc = fmaxf(bm - pd, 0.0f);
  double m[1] = {(double)cc};
  block_sum<1>(m);
  if (t == 0) atomicAdd(&slots[5 * 256 + (blockIdx.x & 255)], m[0]);
}

__global__ void k_final(const double* __restrict__ slots, float* __restrict__ out) {
  int t = threadIdx.x;
  double v[4] = { slots[1 * 256 + t], slots[3 * 256 + t], slots[4 * 256 + t], slots[5 * 256 + t] };
  block_sum<4>(v);
  if (t == 0) {
    float ce_mean = (float)((v[0] + v[1]) / ((double)B_ROWS + v[2]));
    float ml = (float)(v[3] / (double)B_ROWS);
    out[0] = ce_mean + ml;
  }
}

extern "C" void kernel_launch(void* const* d_in, const int* in_sizes, int n_in,
                              void* d_out, int out_size, void* d_ws, size_t ws_size,
                              hipStream_t stream) {
  const float* et  = (const float*)d_in[0];
  const float* ef  = (const float*)d_in[1];
  const float* pr  = (const float*)d_in[2];
  const float* pto = (const float*)d_in[3];
  const float* pfr = (const float*)d_in[4];
  float* out = (float*)d_out;
  if (ws_size < WS_NEEDED) return;   // diagnosable: output stays poisoned

  char* ws = (char*)d_ws;
  u64* pairs1  = (u64*)(ws + OFF_PAIRS1);
  u64* pairs2  = (u64*)(ws + OFF_PAIRS2);
  u64* statT   = (u64*)(ws + OFF_STATT);
  u64* statF   = (u64*)(ws + OFF_STATF);
  float* posd  = (float*)(ws + OFF_POSD);
  u32* hist1   = (u32*)(ws + OFF_HIST1);
  u32* hist2   = (u32*)(ws + OFF_HIST2);
  double* slots= (double*)(ws + OFF_SLOTS);
  u32* totx1   = (u32*)(ws + OFF_TOTX1);
  u32* totx2   = (u32*)(ws + OFF_TOTX2);
  u32* cur1    = (u32*)(ws + OFF_CUR1);
  u32* cur2    = (u32*)(ws + OFF_CUR2);

  hipMemsetAsync(ws + MEMSET_OFF, 0, MEMSET_SZ, stream);

  // Host-side threefry split chain (jax typed key(1) = [0,1]):
  U2 key  = {0u, 1u};
  U2 key1 = tf2x32(key.a, key.b, 0u, 0u);
  U2 sk1  = tf2x32(key.a, key.b, 0u, 1u);
  U2 sk2  = tf2x32(key1.a, key1.b, 0u, 1u);

  k_pos<<<B_ROWS / 256, 256, 0, stream>>>(et, ef, pr, pto, pfr, statT, statF, posd, slots);
  k_count<<<NCHUNK, 256, 0, stream>>>(hist1, hist2, sk1.a, sk1.b, sk2.a, sk2.b);
  k_scan<<<2, 256, 0, stream>>>(hist1, hist2, totx1, totx2, cur1, cur2);
  k_scatter1<<<NCHUNK, 256, 0, stream>>>(pairs1, cur1, sk1.a, sk1.b);
  k_rank1_scatter2<<<NB, 256, 0, stream>>>(pairs1, totx1, pairs2, cur2, sk2.a, sk2.b);
  k_rank2_loss<<<NB, 256, 0, stream>>>(pairs2, totx2, et, ef, statT, statF, slots);
  k_margin<<<B_ROWS / 256, 256, 0, stream>>>(posd, slots);
  k_final<<<1, 256, 0, stream>>>(slots, out);
}

// Round 4
// 127.714 us; speedup vs baseline: 2.0417x; 2.0417x over previous
//
#include <hip/hip_runtime.h>

typedef unsigned long long u64;
typedef unsigned u32;

#define B_ROWS  262144
#define N_NEG   1310720
#define NBK     512           // buckets = key >> 23
#define CAP     3072          // max bucket size (E=2560, sigma=50.6, 10-sigma headroom)
#define NCHUNK  128
#define EPT     40            // N_NEG / (NCHUNK*256)

// ---------------- ws layout (bytes) ----------------
#define OFF_PAIRS1  0u          // N_NEG*4
#define OFF_PAIRS2  5242880u    // N_NEG*4
#define OFF_A1      10485760u   // N_NEG*4
#define OFF_STATT   15728640u   // B*8
#define OFF_FB      17825792u   // B*16
#define OFF_POSD    22020096u   // B*4
#define OFF_HIST    23068672u   // 2*128*512*4 = 524288
#define OFF_TOT     23592960u   // 2*512*4
#define OFF_TOTX    23597056u   // 2*513*4 (stride 513)
#define OFF_SLOTS   23601216u   // 6*256*8
#define WS_NEEDED   23613504u

struct U2 { unsigned a, b; };

// Threefry-2x32, 20 rounds — matches jax/_src/prng.py threefry2x32.
__host__ __device__ inline U2 tf2x32(unsigned k0, unsigned k1, unsigned c0, unsigned c1) {
  unsigned ks2 = k0 ^ k1 ^ 0x1BD11BDAu;
  unsigned x0 = c0 + k0, x1 = c1 + k1;
#define ROTL(x,d) (((x) << (d)) | ((x) >> (32 - (d))))
#define R4(r0,r1,r2,r3) \
  x0 += x1; x1 = ROTL(x1, r0); x1 ^= x0; \
  x0 += x1; x1 = ROTL(x1, r1); x1 ^= x0; \
  x0 += x1; x1 = ROTL(x1, r2); x1 ^= x0; \
  x0 += x1; x1 = ROTL(x1, r3); x1 ^= x0;
  R4(13,15,26,6)   x0 += k1;  x1 += ks2 + 1u;
  R4(17,29,16,24)  x0 += ks2; x1 += k0  + 2u;
  R4(13,15,26,6)   x0 += k0;  x1 += k1  + 3u;
  R4(17,29,16,24)  x0 += k1;  x1 += ks2 + 4u;
  R4(13,15,26,6)   x0 += ks2; x1 += k0  + 5u;
#undef R4
#undef ROTL
  return U2{x0, x1};
}

__device__ inline u32 keyfn(unsigned k0, unsigned k1, u32 i) {
  U2 c = tf2x32(k0, k1, 0u, i);
  return c.a ^ c.b;
}

// ---------- block reduce: thread 0 ends with totals in v[] ----------
template <int N>
__device__ inline void block_sum(double* v) {
  __shared__ double sh[N][4];
  int lane = threadIdx.x & 63, w = threadIdx.x >> 6;
#pragma unroll
  for (int j = 0; j < N; ++j) {
    double x = v[j];
    for (int o = 32; o > 0; o >>= 1) x += __shfl_down(x, o);
    if (lane == 0) sh[j][w] = x;
  }
  __syncthreads();
  if (threadIdx.x == 0)
#pragma unroll
    for (int j = 0; j < N; ++j) v[j] = sh[j][0] + sh[j][1] + sh[j][2] + sh[j][3];
  __syncthreads();
}

// ---------------- pipeline kernels ----------------

// per-chunk bucket histograms for both rounds; hist[(r*NCHUNK+c)*NBK + b]
__global__ __launch_bounds__(256)
void k_count(u32* __restrict__ hist, u32 k10, u32 k11, u32 k20, u32 k21) {
  __shared__ u32 h[2 * NBK];
  int t = threadIdx.x, c = blockIdx.x;
  for (int b = t; b < 2 * NBK; b += 256) h[b] = 0;
  __syncthreads();
  u32 base = c * (EPT * 256);
  for (int e = 0; e < EPT; ++e) {
    u32 i = base + e * 256 + t;
    atomicAdd(&h[keyfn(k10, k11, i) >> 23], 1u);
    atomicAdd(&h[NBK + (keyfn(k20, k21, i) >> 23)], 1u);
  }
  __syncthreads();
  for (int b = t; b < NBK; b += 256) {
    hist[((size_t)c << 9) + b] = h[b];
    hist[((size_t)(NCHUNK + c) << 9) + b] = h[NBK + b];
  }
}

// per-(r,b) exclusive scan over chunks (in place); bucket totals
__global__ void k_scan_chunks(u32* __restrict__ hist, u32* __restrict__ tot) {
  int lane = threadIdx.x;                 // 64
  int r = blockIdx.x >> 3;                // 16 blocks
  int b = (blockIdx.x & 7) * 64 + lane;
  u32 running = 0;
  for (int c = 0; c < NCHUNK; ++c) {
    size_t idx = ((size_t)(r * NCHUNK + c) << 9) + b;
    u32 v = hist[idx];
    hist[idx] = running;
    running += v;
  }
  tot[(r << 9) + b] = running;
}

// exclusive scan of 512 bucket totals per round; totx stride 513, totx[r][512]=N
__global__ void k_scan_tot(const u32* __restrict__ tot, u32* __restrict__ totx) {
  int r = blockIdx.x, t = threadIdx.x;
  u32 l0 = tot[(r << 9) + 2 * t], l1 = tot[(r << 9) + 2 * t + 1];
  u32 s = l0 + l1;
  __shared__ u32 sh[256];
  sh[t] = s; __syncthreads();
  for (int o = 1; o < 256; o <<= 1) {
    u32 x = (t >= o) ? sh[t - o] : 0u; __syncthreads();
    sh[t] += x; __syncthreads();
  }
  u32 run = sh[t] - s;
  totx[r * 513 + 2 * t] = run;
  totx[r * 513 + 2 * t + 1] = run + l0;
  if (t == 255) totx[r * 513 + 512] = run + l0 + l1;
}

// scatter indices into bucket-grouped arrays; per-(chunk,bucket) private ranges
__global__ __launch_bounds__(256)
void k_scatter(u32* __restrict__ pairs1, u32* __restrict__ pairs2,
               const u32* __restrict__ hist, const u32* __restrict__ totx,
               u32 k10, u32 k11, u32 k20, u32 k21) {
  __shared__ u32 cur[2 * NBK];
  int t = threadIdx.x, c = blockIdx.x;
  for (int b = t; b < NBK; b += 256) {
    cur[b]       = totx[b]       + hist[((size_t)c << 9) + b];
    cur[NBK + b] = totx[513 + b] + hist[((size_t)(NCHUNK + c) << 9) + b];
  }
  __syncthreads();
  u32 base = c * (EPT * 256);
  for (int e = 0; e < EPT; ++e) {
    u32 x = base + e * 256 + t;
    u32 b1 = keyfn(k10, k11, x) >> 23;
    pairs1[atomicAdd(&cur[b1], 1u)] = x;
    u32 b2 = keyfn(k20, k21, x) >> 23;
    pairs2[atomicAdd(&cur[NBK + b2], 1u)] = x;
  }
}

// counting-sort ranking within a bucket; composite 44-bit key = (keylow23<<21)|idx
#define RANK_PROLOG(PAIRS, TOTXB, K0, K1)                                     \
  __shared__ u64 karr[CAP];                                                   \
  __shared__ u64 skey[CAP];                                                   \
  __shared__ u32 binx[257];                                                   \
  __shared__ u32 bcur[256];                                                   \
  __shared__ u32 tmp[256];                                                    \
  int t = threadIdx.x, b = blockIdx.x;                                        \
  u32 base = TOTXB[b];                                                        \
  u32 c = TOTXB[b + 1] - base; if (c > CAP) c = CAP;                          \
  binx[t] = 0;                                                                \
  for (int q = 0; q < 12; ++q) {                                              \
    int ii = t + q * 256;                                                     \
    if (ii < (int)c) {                                                        \
      u32 idx = PAIRS[base + ii];                                             \
      u32 key = keyfn(K0, K1, idx);                                           \
      karr[ii] = ((u64)(key & 0x7FFFFFu) << 21) | (u64)idx;                   \
    }                                                                         \
  }                                                                           \
  __syncthreads();                                                            \
  for (int q = 0; q < 12; ++q) {                                              \
    int ii = t + q * 256;                                                     \
    if (ii < (int)c) atomicAdd(&binx[(u32)(karr[ii] >> 36) & 255u], 1u);      \
  }                                                                           \
  __syncthreads();                                                            \
  { u32 v = binx[t]; tmp[t] = v; __syncthreads();                             \
    for (int o = 1; o < 256; o <<= 1) {                                       \
      u32 x = (t >= o) ? tmp[t - o] : 0u; __syncthreads();                    \
      tmp[t] += x; __syncthreads();                                           \
    }                                                                         \
    u32 incl = tmp[t];                                                        \
    binx[t] = incl - v; bcur[t] = incl - v;                                   \
    if (t == 255) binx[256] = incl; }                                         \
  __syncthreads();                                                            \
  for (int q = 0; q < 12; ++q) {                                              \
    int ii = t + q * 256;                                                     \
    if (ii < (int)c) {                                                        \
      u64 k = karr[ii];                                                       \
      skey[atomicAdd(&bcur[(u32)(k >> 36) & 255u], 1u)] = k;                  \
    }                                                                         \
  }                                                                           \
  __syncthreads();

// round-1 rank: A1[final_pos] = original index (dense write per bucket region)
__global__ __launch_bounds__(256)
void k_rank1(const u32* __restrict__ pairs1, const u32* __restrict__ totx,
             u32* __restrict__ A1, u32 k0, u32 k1) {
  RANK_PROLOG(pairs1, totx, k0, k1)
  for (int q = 0; q < 12; ++q) {
    int s = t + q * 256;
    if (s < (int)c) {
      u64 k = skey[s];
      u32 d = (u32)(k >> 36) & 255u;
      u32 lo = binx[d], hi = binx[d + 1];
      u32 r = lo;
      for (u32 e = lo; e < hi; ++e) r += (skey[e] < k) ? 1u : 0u;
      A1[base + r] = (u32)(k & 0x1FFFFFu);
    }
  }
}

// round-2 rank fused with negative-pair loss; i = A1[j] gather composes perms
__global__ __launch_bounds__(256)
void k_rank2_loss(const u32* __restrict__ pairs2, const u32* __restrict__ totx,
                  const u32* __restrict__ A1,
                  const float* __restrict__ et, const u64* __restrict__ statT,
                  const float4* __restrict__ FB, double* __restrict__ slots,
                  u32 k0, u32 k1) {
  RANK_PROLOG(pairs2, totx, k0, k1)
  u32 pv[12], iv[12];
  for (int q = 0; q < 12; ++q) {
    int s = t + q * 256;
    if (s < (int)c) {
      u64 k = skey[s];
      u32 d = (u32)(k >> 36) & 255u;
      u32 lo = binx[d], hi = binx[d + 1];
      u32 r = lo;
      for (u32 e = lo; e < hi; ++e) r += (skey[e] < k) ? 1u : 0u;
      pv[q] = base + r;                    // final permuted position p
      iv[q] = A1[(u32)(k & 0x1FFFFFu)];    // i = perm[p] (random gather)
    }
  }
  double sd = 0.0, sce = 0.0, sn = 0.0;
  for (int q = 0; q < 12; ++q) {
    int s = t + q * 256;
    if (s < (int)c) {
      u32 p = pv[q], i = iv[q];
      u32 a = p / 5u, bb = i / 5u;
      float2 ta = ((const float2*)et)[a];
      float4 fb = FB[bb];
      u64 st = statT[a];
      int at = (int)(st >> 32), af = (int)fb.w;
      float ct = __uint_as_float((u32)st), cf = fb.z;
      float dx = ta.x - fb.x, dy = ta.y - fb.y;
      float dd = sqrtf(dx * dx + dy * dy);
      bool keep = !((af == at) && (cf == ct));
      float pp = 1.0f / (1.0f + dd * dd);
      float qc = fminf(fmaxf(1.0f - pp, 1e-4f), 1.0f);
      float ce = -logf(qc);
      if (keep) { sd += (double)dd; sce += (double)ce; sn += 1.0; }
    }
  }
  double vv[3] = {sd, sce, sn};
  block_sum<3>(vv);
  if (t == 0) {
    int slot = b & 255;
    atomicAdd(&slots[2 * 256 + slot], vv[0]);
    atomicAdd(&slots[3 * 256 + slot], vv[1]);
    atomicAdd(&slots[4 * 256 + slot], vv[2]);
  }
}

// ---------------- loss kernels ----------------
__device__ inline void rowstat(const float* __restrict__ row, int& am, float& conf) {
  float v[10];
  const float2* r2 = (const float2*)row;
#pragma unroll
  for (int j = 0; j < 5; ++j) { float2 x = r2[j]; v[2 * j] = x.x; v[2 * j + 1] = x.y; }
  float m = v[0]; int a = 0;
#pragma unroll
  for (int j = 1; j < 10; ++j) if (v[j] > m) { m = v[j]; a = j; }   // first max, like jnp.argmax
  float s = 0.f;
#pragma unroll
  for (int j = 0; j < 10; ++j) s += expf(v[j] - m);
  am = a;
  conf = 1.0f / s;
}

__global__ __launch_bounds__(256)
void k_pos(const float* __restrict__ et, const float* __restrict__ ef,
           const float* __restrict__ probs,
           const float* __restrict__ pto, const float* __restrict__ pfr,
           u64* __restrict__ statT, float4* __restrict__ FB,
           float* __restrict__ posd, double* __restrict__ slots) {
  int i = blockIdx.x * 256 + threadIdx.x;
  int at, af; float ct, cf;
  rowstat(pto + (size_t)i * 10, at, ct);
  rowstat(pfr + (size_t)i * 10, af, cf);
  float2 a = ((const float2*)et)[i];
  float2 b = ((const float2*)ef)[i];
  statT[i] = ((u64)(u32)at << 32) | (u64)__float_as_uint(ct);
  FB[i] = make_float4(b.x, b.y, cf, (float)af);
  float dx = a.x - b.x, dy = a.y - b.y;
  float d = sqrtf(dx * dx + dy * dy);
  posd[i] = (at == af) ? -d : d;          // sign bit encodes is_pred_same
  float pr = probs[i];
  float p  = 1.0f / (1.0f + d * d);
  float pc = fminf(fmaxf(p, 1e-4f), 1.0f);
  float qc = fminf(fmaxf(1.0f - p, 1e-4f), 1.0f);
  float ce = -pr * logf(pc) - (1.0f - pr) * logf(qc);
  double v[2] = {(double)d, (double)ce};
  block_sum<2>(v);
  if (threadIdx.x == 0) {
    int slot = blockIdx.x & 255;
    atomicAdd(&slots[0 * 256 + slot], v[0]);
    atomicAdd(&slots[1 * 256 + slot], v[1]);
  }
}

__global__ __launch_bounds__(256)
void k_margin(const float* __restrict__ posd, double* __restrict__ slots) {
  int t = threadIdx.x;
  double v[3] = { slots[0 * 256 + t], slots[2 * 256 + t], slots[4 * 256 + t] };
  block_sum<3>(v);
  __shared__ float sbm;
  if (t == 0) {
    float pm = (float)(v[0] / (double)B_ROWS);
    float nm = (float)(v[1] / v[2]);
    sbm = (pm + nm) * 0.5f;
  }
  __syncthreads();
  float bm = sbm;
  int i = blockIdx.x * 256 + t;
  float pd = posd[i];
  float cc = 0.f;
  if (!(__float_as_uint(pd) >> 31)) cc = fmaxf(bm - pd, 0.0f);
  double m[1] = {(double)cc};
  block_sum<1>(m);
  if (t == 0) atomicAdd(&slots[5 * 256 + (blockIdx.x & 255)], m[0]);
}

__global__ void k_final(const double* __restrict__ slots, float* __restrict__ out) {
  int t = threadIdx.x;
  double v[4] = { slots[1 * 256 + t], slots[3 * 256 + t], slots[4 * 256 + t], slots[5 * 256 + t] };
  block_sum<4>(v);
  if (t == 0) {
    float ce_mean = (float)((v[0] + v[1]) / ((double)B_ROWS + v[2]));
    float ml = (float)(v[3] / (double)B_ROWS);
    out[0] = ce_mean + ml;
  }
}

extern "C" void kernel_launch(void* const* d_in, const int* in_sizes, int n_in,
                              void* d_out, int out_size, void* d_ws, size_t ws_size,
                              hipStream_t stream) {
  const float* et  = (const float*)d_in[0];
  const float* ef  = (const float*)d_in[1];
  const float* pr  = (const float*)d_in[2];
  const float* pto = (const float*)d_in[3];
  const float* pfr = (const float*)d_in[4];
  float* out = (float*)d_out;
  if (ws_size < WS_NEEDED) return;   // diagnosable: output stays poisoned

  char* ws = (char*)d_ws;
  u32* pairs1  = (u32*)(ws + OFF_PAIRS1);
  u32* pairs2  = (u32*)(ws + OFF_PAIRS2);
  u32* A1      = (u32*)(ws + OFF_A1);
  u64* statT   = (u64*)(ws + OFF_STATT);
  float4* FB   = (float4*)(ws + OFF_FB);
  float* posd  = (float*)(ws + OFF_POSD);
  u32* hist    = (u32*)(ws + OFF_HIST);
  u32* tot     = (u32*)(ws + OFF_TOT);
  u32* totx    = (u32*)(ws + OFF_TOTX);
  double* slots= (double*)(ws + OFF_SLOTS);

  hipMemsetAsync(slots, 0, 6 * 256 * sizeof(double), stream);

  // Host-side threefry split chain (jax typed key(1) = [0,1]):
  U2 key  = {0u, 1u};
  U2 key1 = tf2x32(key.a, key.b, 0u, 0u);
  U2 sk1  = tf2x32(key.a, key.b, 0u, 1u);
  U2 sk2  = tf2x32(key1.a, key1.b, 0u, 1u);

  k_pos<<<B_ROWS / 256, 256, 0, stream>>>(et, ef, pr, pto, pfr, statT, FB, posd, slots);
  k_count<<<NCHUNK, 256, 0, stream>>>(hist, sk1.a, sk1.b, sk2.a, sk2.b);
  k_scan_chunks<<<16, 64, 0, stream>>>(hist, tot);
  k_scan_tot<<<2, 256, 0, stream>>>(tot, totx);
  k_scatter<<<NCHUNK, 256, 0, stream>>>(pairs1, pairs2, hist, totx,
                                        sk1.a, sk1.b, sk2.a, sk2.b);
  k_rank1<<<NBK, 256, 0, stream>>>(pairs1, totx, A1, sk1.a, sk1.b);
  k_rank2_loss<<<NBK, 256, 0, stream>>>(pairs2, totx + 513, A1, et, statT, FB, slots,
                                        sk2.a, sk2.b);
  k_margin<<<B_ROWS / 256, 256, 0, stream>>>(posd, slots);
  k_final<<<1, 256, 0, stream>>>(slots, out);
}

// Round 5
// 120.313 us; speedup vs baseline: 2.1673x; 1.0615x over previous
//
#include <hip/hip_runtime.h>

typedef unsigned long long u64;
typedef unsigned u32;

#define B_ROWS  262144
#define N_NEG   1310720
#define NBK     512           // buckets = key >> 23
#define CAP     3072          // max bucket size (E=2560, sigma=50.6, 10-sigma headroom)
#define NCHUNK  128
#define EPT     40            // N_NEG / (NCHUNK*256)

// ---------------- ws layout (bytes) ----------------
#define OFF_PAIRS1  0u          // N_NEG*4
#define OFF_PAIRS2  5242880u    // N_NEG*4
#define OFF_BB      10485760u   // N_NEG*4  (stores i/5)
#define OFF_STATT   15728640u   // B*8
#define OFF_FB      17825792u   // B*16
#define OFF_POSD    22020096u   // B*4
#define OFF_HIST    23068672u   // 2*128*512*4 = 524288  layout [r][c][b]
#define OFF_TOTX    23592960u   // 2*513*4 = 4104
#define OFF_SLOTS   23597064u   // 4608 doubles = 36864
#define OFF_ACC     23633928u   // 5 doubles
#define WS_NEEDED   23633968u

// slot bases (in doubles)
#define SL_POSD  0      // 1024
#define SL_POSCE 1024   // 1024
#define SL_NEGD  2048   // 512
#define SL_NEGCE 2560   // 512
#define SL_NEGN  3072   // 512
#define SL_MAR   3584   // 1024

struct U2 { unsigned a, b; };

// Threefry-2x32, 20 rounds — matches jax/_src/prng.py threefry2x32.
__host__ __device__ inline U2 tf2x32(unsigned k0, unsigned k1, unsigned c0, unsigned c1) {
  unsigned ks2 = k0 ^ k1 ^ 0x1BD11BDAu;
  unsigned x0 = c0 + k0, x1 = c1 + k1;
#define ROTL(x,d) (((x) << (d)) | ((x) >> (32 - (d))))
#define R4(r0,r1,r2,r3) \
  x0 += x1; x1 = ROTL(x1, r0); x1 ^= x0; \
  x0 += x1; x1 = ROTL(x1, r1); x1 ^= x0; \
  x0 += x1; x1 = ROTL(x1, r2); x1 ^= x0; \
  x0 += x1; x1 = ROTL(x1, r3); x1 ^= x0;
  R4(13,15,26,6)   x0 += k1;  x1 += ks2 + 1u;
  R4(17,29,16,24)  x0 += ks2; x1 += k0  + 2u;
  R4(13,15,26,6)   x0 += k0;  x1 += k1  + 3u;
  R4(17,29,16,24)  x0 += k1;  x1 += ks2 + 4u;
  R4(13,15,26,6)   x0 += ks2; x1 += k0  + 5u;
#undef R4
#undef ROTL
  return U2{x0, x1};
}

__device__ inline u32 keyfn(unsigned k0, unsigned k1, u32 i) {
  U2 c = tf2x32(k0, k1, 0u, i);
  return c.a ^ c.b;
}

// ---------- block reduce: thread 0 ends with totals in v[] ----------
template <int N>
__device__ inline void block_sum(double* v) {
  __shared__ double sh[N][4];
  int lane = threadIdx.x & 63, w = threadIdx.x >> 6;
#pragma unroll
  for (int j = 0; j < N; ++j) {
    double x = v[j];
    for (int o = 32; o > 0; o >>= 1) x += __shfl_down(x, o);
    if (lane == 0) sh[j][w] = x;
  }
  __syncthreads();
  if (threadIdx.x == 0)
#pragma unroll
    for (int j = 0; j < N; ++j) v[j] = sh[j][0] + sh[j][1] + sh[j][2] + sh[j][3];
  __syncthreads();
}

// ---------------- fused pos-loss + per-chunk histograms ----------------
__device__ inline void rowstat(const float* __restrict__ row, int& am, float& conf) {
  float v[10];
  const float2* r2 = (const float2*)row;
#pragma unroll
  for (int j = 0; j < 5; ++j) { float2 x = r2[j]; v[2 * j] = x.x; v[2 * j + 1] = x.y; }
  float m = v[0]; int a = 0;
#pragma unroll
  for (int j = 1; j < 10; ++j) if (v[j] > m) { m = v[j]; a = j; }   // first max, like jnp.argmax
  float s = 0.f;
#pragma unroll
  for (int j = 0; j < 10; ++j) s += expf(v[j] - m);
  am = a;
  conf = 1.0f / s;
}

__global__ __launch_bounds__(256)
void k_pos(const float* __restrict__ et, const float* __restrict__ ef,
           const float* __restrict__ probs,
           const float* __restrict__ pto, const float* __restrict__ pfr,
           u64* __restrict__ statT, float4* __restrict__ FB,
           float* __restrict__ posd, double* __restrict__ sl,
           u32* __restrict__ hist, u32 k10, u32 k11, u32 k20, u32 k21) {
  __shared__ u32 h[2 * NBK];
  int i = blockIdx.x * 256 + threadIdx.x;
  int at, af; float ct, cf;
  rowstat(pto + (size_t)i * 10, at, ct);
  rowstat(pfr + (size_t)i * 10, af, cf);
  float2 a = ((const float2*)et)[i];
  float2 b = ((const float2*)ef)[i];
  statT[i] = ((u64)(u32)at << 32) | (u64)__float_as_uint(ct);
  FB[i] = make_float4(b.x, b.y, cf, (float)af);
  float dx = a.x - b.x, dy = a.y - b.y;
  float d = sqrtf(dx * dx + dy * dy);
  posd[i] = (at == af) ? -d : d;          // sign bit encodes is_pred_same
  float pr = probs[i];
  float p  = 1.0f / (1.0f + d * d);
  float pc = fminf(fmaxf(p, 1e-4f), 1.0f);
  float qc = fminf(fmaxf(1.0f - p, 1e-4f), 1.0f);
  float ce = -pr * logf(pc) - (1.0f - pr) * logf(qc);
  double v[2] = {(double)d, (double)ce};
  block_sum<2>(v);
  if (threadIdx.x == 0) {
    sl[SL_POSD + blockIdx.x] = v[0];
    sl[SL_POSCE + blockIdx.x] = v[1];
  }
  // ---- fused per-chunk histograms (blocks 0..NCHUNK-1) ----
  if (blockIdx.x < NCHUNK) {
    int t = threadIdx.x, c = blockIdx.x;
    for (int bq = t; bq < 2 * NBK; bq += 256) h[bq] = 0;
    __syncthreads();
    u32 base = c * (EPT * 256);
    for (int e = 0; e < EPT; ++e) {
      u32 x = base + e * 256 + t;
      atomicAdd(&h[keyfn(k10, k11, x) >> 23], 1u);
      atomicAdd(&h[NBK + (keyfn(k20, k21, x) >> 23)], 1u);
    }
    __syncthreads();
    for (int bq = t; bq < NBK; bq += 256) {
      hist[((size_t)c << 9) + bq] = h[bq];
      hist[((size_t)(NCHUNK + c) << 9) + bq] = h[NBK + bq];
    }
  }
}

// fused chunk-scan + bucket-total scan: 2 blocks (one per round) x 512 threads
__global__ __launch_bounds__(512)
void k_scan(u32* __restrict__ hist, u32* __restrict__ totx) {
  int r = blockIdx.x, b = threadIdx.x;    // b = bucket
  u32 running = 0;
#pragma unroll 4
  for (int c = 0; c < NCHUNK; ++c) {
    size_t idx = ((size_t)(r * NCHUNK + c) << 9) + b;
    u32 v = hist[idx];
    hist[idx] = running;
    running += v;
  }
  __shared__ u32 sh[512];
  sh[b] = running; __syncthreads();
  for (int o = 1; o < 512; o <<= 1) {
    u32 x = (b >= o) ? sh[b - o] : 0u; __syncthreads();
    sh[b] += x; __syncthreads();
  }
  totx[r * 513 + b] = sh[b] - running;
  if (b == 511) totx[r * 513 + 512] = sh[511];
}

// scatter indices into bucket-grouped arrays; per-(chunk,bucket) private ranges
__global__ __launch_bounds__(256)
void k_scatter(u32* __restrict__ pairs1, u32* __restrict__ pairs2,
               const u32* __restrict__ hist, const u32* __restrict__ totx,
               u32 k10, u32 k11, u32 k20, u32 k21) {
  __shared__ u32 cur[2 * NBK];
  int t = threadIdx.x, c = blockIdx.x;
  for (int b = t; b < NBK; b += 256) {
    cur[b]       = totx[b]       + hist[((size_t)c << 9) + b];
    cur[NBK + b] = totx[513 + b] + hist[((size_t)(NCHUNK + c) << 9) + b];
  }
  __syncthreads();
  u32 base = c * (EPT * 256);
  for (int e = 0; e < EPT; ++e) {
    u32 x = base + e * 256 + t;
    u32 b1 = keyfn(k10, k11, x) >> 23;
    pairs1[atomicAdd(&cur[b1], 1u)] = x;
    u32 b2 = keyfn(k20, k21, x) >> 23;
    pairs2[atomicAdd(&cur[NBK + b2], 1u)] = x;
  }
}

// counting-sort ranking within a bucket; composite 44-bit key = (keylow23<<21)|idx
#define RANK_PROLOG(PAIRS, TOTXB, K0, K1)                                     \
  __shared__ u64 karr[CAP];                                                   \
  __shared__ u64 skey[CAP];                                                   \
  __shared__ u32 binx[257];                                                   \
  __shared__ u32 bcur[256];                                                   \
  __shared__ u32 tmp[256];                                                    \
  int t = threadIdx.x, b = blockIdx.x;                                        \
  u32 base = TOTXB[b];                                                        \
  u32 c = TOTXB[b + 1] - base; if (c > CAP) c = CAP;                          \
  binx[t] = 0;                                                                \
  for (int q = 0; q < 12; ++q) {                                              \
    int ii = t + q * 256;                                                     \
    if (ii < (int)c) {                                                        \
      u32 idx = PAIRS[base + ii];                                             \
      u32 key = keyfn(K0, K1, idx);                                           \
      karr[ii] = ((u64)(key & 0x7FFFFFu) << 21) | (u64)idx;                   \
    }                                                                         \
  }                                                                           \
  __syncthreads();                                                            \
  for (int q = 0; q < 12; ++q) {                                              \
    int ii = t + q * 256;                                                     \
    if (ii < (int)c) atomicAdd(&binx[(u32)(karr[ii] >> 36) & 255u], 1u);      \
  }                                                                           \
  __syncthreads();                                                            \
  { u32 v = binx[t]; tmp[t] = v; __syncthreads();                             \
    for (int o = 1; o < 256; o <<= 1) {                                       \
      u32 x = (t >= o) ? tmp[t - o] : 0u; __syncthreads();                    \
      tmp[t] += x; __syncthreads();                                           \
    }                                                                         \
    u32 incl = tmp[t];                                                        \
    binx[t] = incl - v; bcur[t] = incl - v;                                   \
    if (t == 255) binx[256] = incl; }                                         \
  __syncthreads();                                                            \
  for (int q = 0; q < 12; ++q) {                                              \
    int ii = t + q * 256;                                                     \
    if (ii < (int)c) {                                                        \
      u64 k = karr[ii];                                                       \
      skey[atomicAdd(&bcur[(u32)(k >> 36) & 255u], 1u)] = k;                  \
    }                                                                         \
  }                                                                           \
  __syncthreads();

// round-1 rank: BB[final_pos] = i/5 (dense write per bucket region)
__global__ __launch_bounds__(256)
void k_rank1(const u32* __restrict__ pairs1, const u32* __restrict__ totx,
             u32* __restrict__ BB, u32 k0, u32 k1) {
  RANK_PROLOG(pairs1, totx, k0, k1)
  for (int q = 0; q < 12; ++q) {
    int s = t + q * 256;
    if (s < (int)c) {
      u64 k = skey[s];
      u32 d = (u32)(k >> 36) & 255u;
      u32 lo = binx[d], hi = binx[d + 1];
      u32 r = lo;
      for (u32 e = lo; e < hi; ++e) r += (skey[e] < k) ? 1u : 0u;
      BB[base + r] = ((u32)(k & 0x1FFFFFu)) / 5u;
    }
  }
}

// round-2 rank fused with negative-pair loss; bb = BB[j] gather composes perms
__global__ __launch_bounds__(256)
void k_rank2_loss(const u32* __restrict__ pairs2, const u32* __restrict__ totx,
                  const u32* __restrict__ BB,
                  const float* __restrict__ et, const u64* __restrict__ statT,
                  const float4* __restrict__ FB, double* __restrict__ sl,
                  u32 k0, u32 k1) {
  RANK_PROLOG(pairs2, totx, k0, k1)
  u32 pv[12], iv[12];
  for (int q = 0; q < 12; ++q) {
    int s = t + q * 256;
    if (s < (int)c) {
      u64 k = skey[s];
      u32 d = (u32)(k >> 36) & 255u;
      u32 lo = binx[d], hi = binx[d + 1];
      u32 r = lo;
      for (u32 e = lo; e < hi; ++e) r += (skey[e] < k) ? 1u : 0u;
      pv[q] = base + r;                    // final permuted position p
      iv[q] = BB[(u32)(k & 0x1FFFFFu)];    // bb = perm-composed from-row
    }
  }
  double sd = 0.0, sce = 0.0, sn = 0.0;
  for (int q = 0; q < 12; ++q) {
    int s = t + q * 256;
    if (s < (int)c) {
      u32 p = pv[q], bb = iv[q];
      u32 a = p / 5u;
      float2 ta = ((const float2*)et)[a];
      float4 fb = FB[bb];
      u64 st = statT[a];
      int at = (int)(st >> 32), af = (int)fb.w;
      float ct = __uint_as_float((u32)st), cf = fb.z;
      float dx = ta.x - fb.x, dy = ta.y - fb.y;
      float dd = sqrtf(dx * dx + dy * dy);
      bool keep = !((af == at) && (cf == ct));
      float pp = 1.0f / (1.0f + dd * dd);
      float qc = fminf(fmaxf(1.0f - pp, 1e-4f), 1.0f);
      float ce = -logf(qc);
      if (keep) { sd += (double)dd; sce += (double)ce; sn += 1.0; }
    }
  }
  double vv[3] = {sd, sce, sn};
  block_sum<3>(vv);
  if (t == 0) {
    sl[SL_NEGD + b] = vv[0];
    sl[SL_NEGCE + b] = vv[1];
    sl[SL_NEGN + b] = vv[2];
  }
}

// reduce pos/neg slots -> acc[5]
__global__ void k_combine(const double* __restrict__ sl, double* __restrict__ acc) {
  int t = threadIdx.x;
  double v[5];
  v[0] = sl[SL_POSD + t] + sl[SL_POSD + 256 + t] + sl[SL_POSD + 512 + t] + sl[SL_POSD + 768 + t];
  v[1] = sl[SL_POSCE + t] + sl[SL_POSCE + 256 + t] + sl[SL_POSCE + 512 + t] + sl[SL_POSCE + 768 + t];
  v[2] = sl[SL_NEGD + t] + sl[SL_NEGD + 256 + t];
  v[3] = sl[SL_NEGCE + t] + sl[SL_NEGCE + 256 + t];
  v[4] = sl[SL_NEGN + t] + sl[SL_NEGN + 256 + t];
  block_sum<5>(v);
  if (t == 0)
    for (int j = 0; j < 5; ++j) acc[j] = v[j];
}

__global__ __launch_bounds__(256)
void k_margin(const float* __restrict__ posd, const double* __restrict__ acc,
              double* __restrict__ sl) {
  int t = threadIdx.x;
  float pm = (float)(acc[0] / (double)B_ROWS);
  float nm = (float)(acc[2] / acc[4]);
  float bm = (pm + nm) * 0.5f;
  int i = blockIdx.x * 256 + t;
  float pd = posd[i];
  float cc = 0.f;
  if (!(__float_as_uint(pd) >> 31)) cc = fmaxf(bm - pd, 0.0f);
  double m[1] = {(double)cc};
  block_sum<1>(m);
  if (t == 0) sl[SL_MAR + blockIdx.x] = m[0];
}

__global__ void k_final(const double* __restrict__ sl, const double* __restrict__ acc,
                        float* __restrict__ out) {
  int t = threadIdx.x;
  double v[1] = { sl[SL_MAR + t] + sl[SL_MAR + 256 + t] + sl[SL_MAR + 512 + t] + sl[SL_MAR + 768 + t] };
  block_sum<1>(v);
  if (t == 0) {
    float ce_mean = (float)((acc[1] + acc[3]) / ((double)B_ROWS + acc[4]));
    float ml = (float)(v[0] / (double)B_ROWS);
    out[0] = ce_mean + ml;
  }
}

extern "C" void kernel_launch(void* const* d_in, const int* in_sizes, int n_in,
                              void* d_out, int out_size, void* d_ws, size_t ws_size,
                              hipStream_t stream) {
  const float* et  = (const float*)d_in[0];
  const float* ef  = (const float*)d_in[1];
  const float* pr  = (const float*)d_in[2];
  const float* pto = (const float*)d_in[3];
  const float* pfr = (const float*)d_in[4];
  float* out = (float*)d_out;
  if (ws_size < WS_NEEDED) return;   // diagnosable: output stays poisoned

  char* ws = (char*)d_ws;
  u32* pairs1  = (u32*)(ws + OFF_PAIRS1);
  u32* pairs2  = (u32*)(ws + OFF_PAIRS2);
  u32* BB      = (u32*)(ws + OFF_BB);
  u64* statT   = (u64*)(ws + OFF_STATT);
  float4* FB   = (float4*)(ws + OFF_FB);
  float* posd  = (float*)(ws + OFF_POSD);
  u32* hist    = (u32*)(ws + OFF_HIST);
  u32* totx    = (u32*)(ws + OFF_TOTX);
  double* sl   = (double*)(ws + OFF_SLOTS);
  double* acc  = (double*)(ws + OFF_ACC);

  // Host-side threefry split chain (jax typed key(1) = [0,1]):
  U2 key  = {0u, 1u};
  U2 key1 = tf2x32(key.a, key.b, 0u, 0u);
  U2 sk1  = tf2x32(key.a, key.b, 0u, 1u);
  U2 sk2  = tf2x32(key1.a, key1.b, 0u, 1u);

  k_pos<<<B_ROWS / 256, 256, 0, stream>>>(et, ef, pr, pto, pfr, statT, FB, posd, sl,
                                          hist, sk1.a, sk1.b, sk2.a, sk2.b);
  k_scan<<<2, 512, 0, stream>>>(hist, totx);
  k_scatter<<<NCHUNK, 256, 0, stream>>>(pairs1, pairs2, hist, totx,
                                        sk1.a, sk1.b, sk2.a, sk2.b);
  k_rank1<<<NBK, 256, 0, stream>>>(pairs1, totx, BB, sk1.a, sk1.b);
  k_rank2_loss<<<NBK, 256, 0, stream>>>(pairs2, totx + 513, BB, et, statT, FB, sl,
                                        sk2.a, sk2.b);
  k_combine<<<1, 256, 0, stream>>>(sl, acc);
  k_margin<<<B_ROWS / 256, 256, 0, stream>>>(posd, acc, sl);
  k_final<<<1, 256, 0, stream>>>(sl, acc, out);
}

// Round 6
// 102.494 us; speedup vs baseline: 2.5441x; 1.1739x over previous
//
#include <hip/hip_runtime.h>

typedef unsigned long long u64;
typedef unsigned u32;

#define B_ROWS  262144
#define N_NEG   1310720
#define NBK     512           // buckets = key >> 23
#define CAP     3072          // max bucket size (E=2560; counts deterministic, verified <=3072 R4/R5)
#define NCHUNK  256
#define EPT     20            // N_NEG / (NCHUNK*256)

// ---------------- ws layout (bytes) ----------------
#define OFF_P1     0u           // NBK*CAP*4 = 6291456
#define OFF_P2     6291456u     // NBK*CAP*8 = 12582912
#define OFF_STATT  18874368u    // B*8
#define OFF_FB     20971520u    // B*16
#define OFF_POSD   25165824u    // B*4
#define OFF_GC     26214400u    // gcnt1[512] + gcnt2[512] = 4096 (memset to 0)
#define OFF_SLOTS  26218496u    // 4608 doubles = 36864
#define WS_NEEDED  26255360u

// slot bases (in doubles)
#define SL_POSD  0      // 1024
#define SL_POSCE 1024   // 1024
#define SL_NEGD  2048   // 512
#define SL_NEGCE 2560   // 512
#define SL_NEGN  3072   // 512
#define SL_MAR   3584   // 1024

struct U2 { unsigned a, b; };

// Threefry-2x32, 20 rounds — matches jax/_src/prng.py threefry2x32.
__host__ __device__ inline U2 tf2x32(unsigned k0, unsigned k1, unsigned c0, unsigned c1) {
  unsigned ks2 = k0 ^ k1 ^ 0x1BD11BDAu;
  unsigned x0 = c0 + k0, x1 = c1 + k1;
#define ROTL(x,d) (((x) << (d)) | ((x) >> (32 - (d))))
#define R4(r0,r1,r2,r3) \
  x0 += x1; x1 = ROTL(x1, r0); x1 ^= x0; \
  x0 += x1; x1 = ROTL(x1, r1); x1 ^= x0; \
  x0 += x1; x1 = ROTL(x1, r2); x1 ^= x0; \
  x0 += x1; x1 = ROTL(x1, r3); x1 ^= x0;
  R4(13,15,26,6)   x0 += k1;  x1 += ks2 + 1u;
  R4(17,29,16,24)  x0 += ks2; x1 += k0  + 2u;
  R4(13,15,26,6)   x0 += k0;  x1 += k1  + 3u;
  R4(17,29,16,24)  x0 += k1;  x1 += ks2 + 4u;
  R4(13,15,26,6)   x0 += ks2; x1 += k0  + 5u;
#undef R4
#undef ROTL
  return U2{x0, x1};
}

__device__ inline u32 keyfn(unsigned k0, unsigned k1, u32 i) {
  U2 c = tf2x32(k0, k1, 0u, i);
  return c.a ^ c.b;
}

// ---------- block reduce: thread 0 ends with totals in v[] ----------
template <int N>
__device__ inline void block_sum(double* v) {
  __shared__ double sh[N][4];
  int lane = threadIdx.x & 63, w = threadIdx.x >> 6;
#pragma unroll
  for (int j = 0; j < N; ++j) {
    double x = v[j];
    for (int o = 32; o > 0; o >>= 1) x += __shfl_down(x, o);
    if (lane == 0) sh[j][w] = x;
  }
  __syncthreads();
  if (threadIdx.x == 0)
#pragma unroll
    for (int j = 0; j < N; ++j) v[j] = sh[j][0] + sh[j][1] + sh[j][2] + sh[j][3];
  __syncthreads();
}

// ---------------- k_pos: pos loss + round-1 chunk hist/reserve/scatter ----------------
__device__ inline void rowstat(const float* __restrict__ row, int& am, float& conf) {
  float v[10];
  const float2* r2 = (const float2*)row;
#pragma unroll
  for (int j = 0; j < 5; ++j) { float2 x = r2[j]; v[2 * j] = x.x; v[2 * j + 1] = x.y; }
  float m = v[0]; int a = 0;
#pragma unroll
  for (int j = 1; j < 10; ++j) if (v[j] > m) { m = v[j]; a = j; }   // first max, like jnp.argmax
  float s = 0.f;
#pragma unroll
  for (int j = 0; j < 10; ++j) s += expf(v[j] - m);
  am = a;
  conf = 1.0f / s;
}

__global__ __launch_bounds__(256)
void k_pos(const float* __restrict__ et, const float* __restrict__ ef,
           const float* __restrict__ probs,
           const float* __restrict__ pto, const float* __restrict__ pfr,
           u64* __restrict__ statT, float4* __restrict__ FB,
           float* __restrict__ posd, double* __restrict__ sl,
           u32* __restrict__ pairs1, u32* __restrict__ gcnt1,
           u32 k10, u32 k11) {
  __shared__ u32 hh[NBK];
  int i = blockIdx.x * 256 + threadIdx.x;
  int at, af; float ct, cf;
  rowstat(pto + (size_t)i * 10, at, ct);
  rowstat(pfr + (size_t)i * 10, af, cf);
  float2 a = ((const float2*)et)[i];
  float2 b = ((const float2*)ef)[i];
  statT[i] = ((u64)(u32)at << 32) | (u64)__float_as_uint(ct);
  FB[i] = make_float4(b.x, b.y, cf, (float)af);
  float dx = a.x - b.x, dy = a.y - b.y;
  float d = sqrtf(dx * dx + dy * dy);
  posd[i] = (at == af) ? -d : d;          // sign bit encodes is_pred_same
  float pr = probs[i];
  float p  = 1.0f / (1.0f + d * d);
  float pc = fminf(fmaxf(p, 1e-4f), 1.0f);
  float qc = fminf(fmaxf(1.0f - p, 1e-4f), 1.0f);
  float ce = -pr * logf(pc) - (1.0f - pr) * logf(qc);
  double v[2] = {(double)d, (double)ce};
  block_sum<2>(v);
  if (threadIdx.x == 0) {
    sl[SL_POSD + blockIdx.x] = v[0];
    sl[SL_POSCE + blockIdx.x] = v[1];
  }
  // ---- round-1 chunk: hist -> reserve -> scatter (blocks 0..NCHUNK-1) ----
  if (blockIdx.x < NCHUNK) {
    int t = threadIdx.x, ch = blockIdx.x;
    for (int bq = t; bq < NBK; bq += 256) hh[bq] = 0;
    __syncthreads();
    u32 base = ch * (EPT * 256);
    for (int e = 0; e < EPT; ++e) {
      u32 x = base + e * 256 + t;
      atomicAdd(&hh[keyfn(k10, k11, x) >> 23], 1u);
    }
    __syncthreads();
    for (int bq = t; bq < NBK; bq += 256) {
      u32 hv = hh[bq];
      u32 st = hv ? atomicAdd(&gcnt1[bq], hv) : 0u;
      hh[bq] = bq * CAP + st;
    }
    __syncthreads();
    for (int e = 0; e < EPT; ++e) {
      u32 x = base + e * 256 + t;
      u32 b1 = keyfn(k10, k11, x) >> 23;
      pairs1[atomicAdd(&hh[b1], 1u)] = x;
    }
  }
}

// ---------------- rank1 (+fused round-2 scatter) ----------------
// composite1 = (key1low23 << 21) | i ; digit bits [43:36] = key1 bits [22:15]
__global__ __launch_bounds__(256)
void k_rank1_scatter2(const u32* __restrict__ pairs1, const u32* __restrict__ gcnt1,
                      u32* __restrict__ gcnt2, u64* __restrict__ pairs2,
                      u32 k10, u32 k11, u32 k20, u32 k21) {
  __shared__ u64 karr[CAP];
  __shared__ u64 skey[CAP];
  __shared__ u32 binx[257];
  __shared__ u32 bcur[256];
  __shared__ u32 tmp[256];
  __shared__ u32 hc[NBK];
  __shared__ u32 sbase;
  int t = threadIdx.x, b = blockIdx.x;

  // base1 = exclusive prefix of gcnt1 over buckets < b
  u32 l0 = gcnt1[2 * t], l1 = gcnt1[2 * t + 1];
  u32 s2 = l0 + l1;
  tmp[t] = s2; __syncthreads();
  for (int o = 1; o < 256; o <<= 1) {
    u32 x = (t >= o) ? tmp[t - o] : 0u; __syncthreads();
    tmp[t] += x; __syncthreads();
  }
  if (t == (b >> 1)) sbase = (tmp[t] - s2) + ((b & 1) ? l0 : 0u);
  binx[t] = 0;
  if (t == 0) binx[256] = 0;
  __syncthreads();
  u32 base1 = sbase;
  u32 c = gcnt1[b]; if (c > CAP) c = CAP;

  for (int q = 0; q < 12; ++q) {
    int ii = t + q * 256;
    if (ii < (int)c) {
      u32 idx = pairs1[(size_t)b * CAP + ii];
      u32 key = keyfn(k10, k11, idx);
      karr[ii] = ((u64)(key & 0x7FFFFFu) << 21) | (u64)idx;
    }
  }
  __syncthreads();
  for (int q = 0; q < 12; ++q) {
    int ii = t + q * 256;
    if (ii < (int)c) atomicAdd(&binx[(u32)(karr[ii] >> 36) & 255u], 1u);
  }
  __syncthreads();
  { u32 v = binx[t]; tmp[t] = v; __syncthreads();
    for (int o = 1; o < 256; o <<= 1) {
      u32 x = (t >= o) ? tmp[t - o] : 0u; __syncthreads();
      tmp[t] += x; __syncthreads();
    }
    u32 incl = tmp[t];
    binx[t] = incl - v; bcur[t] = incl - v;
    if (t == 255) binx[256] = incl; }
  __syncthreads();
  for (int q = 0; q < 12; ++q) {
    int ii = t + q * 256;
    if (ii < (int)c) {
      u64 k = karr[ii];
      skey[atomicAdd(&bcur[(u32)(k >> 36) & 255u], 1u)] = k;
    }
  }
  __syncthreads();
  // rank -> j ; repack karr[s] = (j << 18) | bb  (owner-thread reuse, no race)
  for (int q = 0; q < 12; ++q) {
    int s = t + q * 256;
    if (s < (int)c) {
      u64 k = skey[s];
      u32 d = (u32)(k >> 36) & 255u;
      u32 lo = binx[d], hi = binx[d + 1];
      u32 r = lo;
      for (u32 e = lo; e < hi; ++e) r += (skey[e] < k) ? 1u : 0u;
      u32 j = base1 + r;
      u32 i = (u32)k & 0x1FFFFFu;
      karr[s] = ((u64)j << 18) | (u64)(i / 5u);
    }
  }
  // round-2: hist -> reserve -> scatter packed tuples
  for (int bq = t; bq < NBK; bq += 256) hc[bq] = 0;
  __syncthreads();
  for (int q = 0; q < 12; ++q) {
    int s = t + q * 256;
    if (s < (int)c) {
      u32 j = (u32)(karr[s] >> 18);
      atomicAdd(&hc[keyfn(k20, k21, j) >> 23], 1u);
    }
  }
  __syncthreads();
  for (int bq = t; bq < NBK; bq += 256) {
    u32 hv = hc[bq];
    u32 st = hv ? atomicAdd(&gcnt2[bq], hv) : 0u;
    hc[bq] = bq * CAP + st;
  }
  __syncthreads();
  for (int q = 0; q < 12; ++q) {
    int s = t + q * 256;
    if (s < (int)c) {
      u64 jb = karr[s];
      u32 j = (u32)(jb >> 18);
      u32 key2 = keyfn(k20, k21, j);
      u32 slot = atomicAdd(&hc[key2 >> 23], 1u);
      pairs2[slot] = ((u64)(key2 & 0x7FFFFFu) << 39) | jb;   // jb = (j<<18)|bb
    }
  }
}

// ---------------- rank2 + negative loss ----------------
// packed = (key2low23 << 39) | (j << 18) | bb ; digit bits [61:54] = key2 bits [22:15]
__global__ __launch_bounds__(256)
void k_rank2_loss(const u64* __restrict__ pairs2, const u32* __restrict__ gcnt2,
                  const float* __restrict__ et, const u64* __restrict__ statT,
                  const float4* __restrict__ FB, double* __restrict__ sl) {
  __shared__ u64 karr[CAP];
  __shared__ u64 skey[CAP];
  __shared__ u32 binx[257];
  __shared__ u32 bcur[256];
  __shared__ u32 tmp[256];
  __shared__ u32 sbase;
  int t = threadIdx.x, b = blockIdx.x;

  u32 l0 = gcnt2[2 * t], l1 = gcnt2[2 * t + 1];
  u32 s2 = l0 + l1;
  tmp[t] = s2; __syncthreads();
  for (int o = 1; o < 256; o <<= 1) {
    u32 x = (t >= o) ? tmp[t - o] : 0u; __syncthreads();
    tmp[t] += x; __syncthreads();
  }
  if (t == (b >> 1)) sbase = (tmp[t] - s2) + ((b & 1) ? l0 : 0u);
  binx[t] = 0;
  if (t == 0) binx[256] = 0;
  __syncthreads();
  u32 base2 = sbase;
  u32 c = gcnt2[b]; if (c > CAP) c = CAP;

  for (int q = 0; q < 12; ++q) {
    int ii = t + q * 256;
    if (ii < (int)c) karr[ii] = pairs2[(size_t)b * CAP + ii];
  }
  __syncthreads();
  for (int q = 0; q < 12; ++q) {
    int ii = t + q * 256;
    if (ii < (int)c) atomicAdd(&binx[(u32)(karr[ii] >> 54) & 255u], 1u);
  }
  __syncthreads();
  { u32 v = binx[t]; tmp[t] = v; __syncthreads();
    for (int o = 1; o < 256; o <<= 1) {
      u32 x = (t >= o) ? tmp[t - o] : 0u; __syncthreads();
      tmp[t] += x; __syncthreads();
    }
    u32 incl = tmp[t];
    binx[t] = incl - v; bcur[t] = incl - v;
    if (t == 255) binx[256] = incl; }
  __syncthreads();
  for (int q = 0; q < 12; ++q) {
    int ii = t + q * 256;
    if (ii < (int)c) {
      u64 k = karr[ii];
      skey[atomicAdd(&bcur[(u32)(k >> 54) & 255u], 1u)] = k;
    }
  }
  __syncthreads();
  double sd = 0.0, sce = 0.0, sn = 0.0;
  for (int q = 0; q < 12; ++q) {
    int s = t + q * 256;
    if (s < (int)c) {
      u64 k = skey[s];
      u32 d = (u32)(k >> 54) & 255u;
      u32 lo = binx[d], hi = binx[d + 1];
      u32 r = lo;
      for (u32 e = lo; e < hi; ++e) r += (skey[e] < k) ? 1u : 0u;
      u32 p = base2 + r;                  // final permuted position
      u32 bb = (u32)k & 0x3FFFFu;         // from-row (perm-composed)
      u32 a = p / 5u;
      float2 ta = ((const float2*)et)[a];
      float4 fb = FB[bb];
      u64 st = statT[a];
      int at = (int)(st >> 32), af = (int)fb.w;
      float ct = __uint_as_float((u32)st), cf = fb.z;
      float dx = ta.x - fb.x, dy = ta.y - fb.y;
      float dd = sqrtf(dx * dx + dy * dy);
      bool keep = !((af == at) && (cf == ct));
      float pp = 1.0f / (1.0f + dd * dd);
      float qc = fminf(fmaxf(1.0f - pp, 1e-4f), 1.0f);
      float ce = -logf(qc);
      if (keep) { sd += (double)dd; sce += (double)ce; sn += 1.0; }
    }
  }
  double vv[3] = {sd, sce, sn};
  block_sum<3>(vv);
  if (t == 0) {
    sl[SL_NEGD + b] = vv[0];
    sl[SL_NEGCE + b] = vv[1];
    sl[SL_NEGN + b] = vv[2];
  }
}

// ---------------- margin (inline combine) + final ----------------
__global__ __launch_bounds__(256)
void k_margin(const float* __restrict__ posd, double* sl) {
  int t = threadIdx.x;
  double v[3];
  v[0] = sl[SL_POSD + t] + sl[SL_POSD + 256 + t] + sl[SL_POSD + 512 + t] + sl[SL_POSD + 768 + t];
  v[1] = sl[SL_NEGD + t] + sl[SL_NEGD + 256 + t];
  v[2] = sl[SL_NEGN + t] + sl[SL_NEGN + 256 + t];
  block_sum<3>(v);
  __shared__ float sbm;
  if (t == 0) {
    float pm = (float)(v[0] / (double)B_ROWS);
    float nm = (float)(v[1] / v[2]);
    sbm = (pm + nm) * 0.5f;
  }
  __syncthreads();
  float bm = sbm;
  int i = blockIdx.x * 256 + t;
  float pd = posd[i];
  float cc = 0.f;
  if (!(__float_as_uint(pd) >> 31)) cc = fmaxf(bm - pd, 0.0f);
  double m[1] = {(double)cc};
  block_sum<1>(m);
  if (t == 0) sl[SL_MAR + blockIdx.x] = m[0];
}

__global__ void k_final(const double* __restrict__ sl, float* __restrict__ out) {
  int t = threadIdx.x;
  double v[4];
  v[0] = sl[SL_POSCE + t] + sl[SL_POSCE + 256 + t] + sl[SL_POSCE + 512 + t] + sl[SL_POSCE + 768 + t];
  v[1] = sl[SL_NEGCE + t] + sl[SL_NEGCE + 256 + t];
  v[2] = sl[SL_NEGN + t] + sl[SL_NEGN + 256 + t];
  v[3] = sl[SL_MAR + t] + sl[SL_MAR + 256 + t] + sl[SL_MAR + 512 + t] + sl[SL_MAR + 768 + t];
  block_sum<4>(v);
  if (t == 0) {
    float ce_mean = (float)((v[0] + v[1]) / ((double)B_ROWS + v[2]));
    float ml = (float)(v[3] / (double)B_ROWS);
    out[0] = ce_mean + ml;
  }
}

extern "C" void kernel_launch(void* const* d_in, const int* in_sizes, int n_in,
                              void* d_out, int out_size, void* d_ws, size_t ws_size,
                              hipStream_t stream) {
  const float* et  = (const float*)d_in[0];
  const float* ef  = (const float*)d_in[1];
  const float* pr  = (const float*)d_in[2];
  const float* pto = (const float*)d_in[3];
  const float* pfr = (const float*)d_in[4];
  float* out = (float*)d_out;
  if (ws_size < WS_NEEDED) return;   // diagnosable: output stays poisoned

  char* ws = (char*)d_ws;
  u32* pairs1  = (u32*)(ws + OFF_P1);
  u64* pairs2  = (u64*)(ws + OFF_P2);
  u64* statT   = (u64*)(ws + OFF_STATT);
  float4* FB   = (float4*)(ws + OFF_FB);
  float* posd  = (float*)(ws + OFF_POSD);
  u32* gcnt1   = (u32*)(ws + OFF_GC);
  u32* gcnt2   = (u32*)(ws + OFF_GC + NBK * 4);
  double* sl   = (double*)(ws + OFF_SLOTS);

  hipMemsetAsync(ws + OFF_GC, 0, 2 * NBK * 4, stream);

  // Host-side threefry split chain (jax typed key(1) = [0,1]):
  U2 key  = {0u, 1u};
  U2 key1 = tf2x32(key.a, key.b, 0u, 0u);
  U2 sk1  = tf2x32(key.a, key.b, 0u, 1u);
  U2 sk2  = tf2x32(key1.a, key1.b, 0u, 1u);

  k_pos<<<B_ROWS / 256, 256, 0, stream>>>(et, ef, pr, pto, pfr, statT, FB, posd, sl,
                                          pairs1, gcnt1, sk1.a, sk1.b);
  k_rank1_scatter2<<<NBK, 256, 0, stream>>>(pairs1, gcnt1, gcnt2, pairs2,
                                            sk1.a, sk1.b, sk2.a, sk2.b);
  k_rank2_loss<<<NBK, 256, 0, stream>>>(pairs2, gcnt2, et, statT, FB, sl);
  k_margin<<<B_ROWS / 256, 256, 0, stream>>>(posd, sl);
  k_final<<<1, 256, 0, stream>>>(sl, out);
}